// Round 1
// baseline (819.259 us; speedup 1.0000x reference)
//
#include <hip/hip_runtime.h>
#include <math.h>

#define B_ 512
#define N_ 62
#define V_ (B_ * N_)      // 31744
#define D_ 512            // C*T = in dim = H*OUT
#define HEADS_ 4
#define OUT_ 128
#define TOPK_ 8

// ---------------------------------------------------------------------------
// Stage 1: S[b,n,m] = tanh( (einsum('bnct,t',x,W1) @ W2) @ V_sp + b_sp )
// one wave per (b,n)
// ---------------------------------------------------------------------------
__global__ __launch_bounds__(64) void spatial_S(
    const float* __restrict__ x, const float* __restrict__ W1,
    const float* __restrict__ W2, const float* __restrict__ bsp,
    const float* __restrict__ Vsp, float* __restrict__ S)
{
    int blk = blockIdx.x;            // b*62 + n
    int n = blk % N_;
    int lane = threadIdx.x;          // 0..63
    const float* xr = x + (size_t)blk * 512;   // [8][64] row
    float w1 = W1[lane];             // T = 64 exactly

    float y[8];
#pragma unroll
    for (int c = 0; c < 8; ++c) {
        float p = xr[c * 64 + lane] * w1;
#pragma unroll
        for (int off = 32; off; off >>= 1) p += __shfl_xor(p, off);
        y[c] = p;                    // broadcast to all lanes
    }

    __shared__ float pr[N_];
    if (lane < N_) {
        float acc = 0.f;
#pragma unroll
        for (int c = 0; c < 8; ++c) acc += y[c] * W2[c * N_ + lane];
        pr[lane] = acc;
    }
    __syncthreads();
    if (lane < N_) {
        float acc = bsp[n * N_ + lane];
        for (int k = 0; k < N_; ++k) acc += pr[k] * Vsp[k * N_ + lane];
        S[(size_t)blk * N_ + lane] = tanhf(acc);
    }
}

// ---------------------------------------------------------------------------
// Stage 2: BatchNorm1d stats over axes (b, m) per channel n  -> scale/shift
// adj = S*scale[n] + shift[n]
// ---------------------------------------------------------------------------
__global__ __launch_bounds__(256) void bn_stats(
    const float* __restrict__ S, const float* __restrict__ bnw,
    const float* __restrict__ bnb, float* __restrict__ scale,
    float* __restrict__ shift)
{
    int n = blockIdx.x;
    double s = 0.0, s2 = 0.0;
    for (int i = threadIdx.x; i < B_ * N_; i += 256) {
        int b = i / N_, m = i - b * N_;
        float v = S[((size_t)b * N_ + n) * N_ + m];
        s += v; s2 += (double)v * v;
    }
    __shared__ double sh[256], sh2[256];
    sh[threadIdx.x] = s; sh2[threadIdx.x] = s2;
    __syncthreads();
    for (int off = 128; off; off >>= 1) {
        if (threadIdx.x < off) {
            sh[threadIdx.x] += sh[threadIdx.x + off];
            sh2[threadIdx.x] += sh2[threadIdx.x + off];
        }
        __syncthreads();
    }
    if (threadIdx.x == 0) {
        const double cnt = (double)(B_ * N_);
        double mean = sh[0] / cnt;
        double var = sh2[0] / cnt - mean * mean;
        float inv = (float)(1.0 / sqrt(var + 1e-5));
        scale[n] = bnw[n] * inv;
        shift[n] = bnb[n] - (float)mean * bnw[n] * inv;
    }
}

// ---------------------------------------------------------------------------
// Stage 3: per-row top-8 -> transposed incoming-edge bitmask maskT[b*62+dst]
// (bit s set iff edge s->dst exists, incl. self loop)
// one wave per (b,n); ties broken toward smaller index like jax.lax.top_k
// ---------------------------------------------------------------------------
__global__ __launch_bounds__(64) void topk_mask(
    const float* __restrict__ S, const float* __restrict__ scale,
    const float* __restrict__ shift, unsigned long long* __restrict__ maskT)
{
    int blk = blockIdx.x;            // b*62 + n
    int b = blk / N_, n = blk - b * N_;
    int lane = threadIdx.x;
    float v = (lane < N_) ? S[(size_t)blk * N_ + lane] * scale[n] + shift[n]
                          : -INFINITY;
    bool sel = false;
#pragma unroll
    for (int k = 0; k < TOPK_; ++k) {
        float mv = v; int mi = lane;
#pragma unroll
        for (int off = 32; off; off >>= 1) {
            float ov = __shfl_xor(mv, off);
            int   oi = __shfl_xor(mi, off);
            if (ov > mv || (ov == mv && oi < mi)) { mv = ov; mi = oi; }
        }
        if (lane == mi) { sel = true; v = -INFINITY; }
    }
    unsigned long long row = __ballot(sel) | (1ull << n);  // self loop union
    if (lane < N_ && ((row >> lane) & 1ull))
        atomicOr(&maskT[(size_t)b * N_ + lane], 1ull << n);
}

__global__ __launch_bounds__(256) void zero_u64(unsigned long long* p, int n)
{
    int i = blockIdx.x * 256 + threadIdx.x;
    if (i < n) p[i] = 0ull;
}

// ---------------------------------------------------------------------------
// fp32 GEMM:  C[v,o] = sum_i A[v,i] * W[o,i]   (A:[M,512], W:[512,512] row-major)
// 128x128 tile, BK=16, k-major LDS (pad 132), 8x8 micro-tile, 256 threads
// M = 31744 = 248*128 exactly, N = K = 512 -> no edge guards.
// ---------------------------------------------------------------------------
#define BM 128
#define BN 128
#define BK 16
__global__ __launch_bounds__(256) void gemm_f32(
    const float* __restrict__ A, const float* __restrict__ W,
    float* __restrict__ C)
{
    __shared__ float As[BK][BM + 4];   // row stride 132 floats (16B-aligned)
    __shared__ float Bs[BK][BN + 4];

    int tid = threadIdx.x;
    int tx = tid & 15, ty = tid >> 4;
    int bn = blockIdx.x * BN;          // col block (fastest -> A-panel reuse)
    int bm = blockIdx.y * BM;          // row block

    float acc[8][8];
#pragma unroll
    for (int j = 0; j < 8; ++j)
#pragma unroll
        for (int l = 0; l < 8; ++l) acc[j][l] = 0.f;

    int lr = tid >> 2;                 // 0..63 (rows lr and lr+64)
    int lk = (tid & 3) << 2;           // k offset {0,4,8,12}
    const float* Ap = A + (size_t)(bm + lr) * 512 + lk;
    const float* Wp = W + (size_t)(bn + lr) * 512 + lk;

    float4 a0 = *(const float4*)(Ap);
    float4 a1 = *(const float4*)(Ap + 64 * 512);
    float4 b0 = *(const float4*)(Wp);
    float4 b1 = *(const float4*)(Wp + 64 * 512);

    for (int kt = 0; kt < 512; kt += BK) {
        __syncthreads();
        As[lk + 0][lr] = a0.x; As[lk + 1][lr] = a0.y;
        As[lk + 2][lr] = a0.z; As[lk + 3][lr] = a0.w;
        As[lk + 0][lr + 64] = a1.x; As[lk + 1][lr + 64] = a1.y;
        As[lk + 2][lr + 64] = a1.z; As[lk + 3][lr + 64] = a1.w;
        Bs[lk + 0][lr] = b0.x; Bs[lk + 1][lr] = b0.y;
        Bs[lk + 2][lr] = b0.z; Bs[lk + 3][lr] = b0.w;
        Bs[lk + 0][lr + 64] = b1.x; Bs[lk + 1][lr + 64] = b1.y;
        Bs[lk + 2][lr + 64] = b1.z; Bs[lk + 3][lr + 64] = b1.w;
        __syncthreads();

        int ktn = (kt + BK) & 511;     // wraps to 0 on last iter (discarded)
        a0 = *(const float4*)(Ap + ktn);
        a1 = *(const float4*)(Ap + ktn + 64 * 512);
        b0 = *(const float4*)(Wp + ktn);
        b1 = *(const float4*)(Wp + ktn + 64 * 512);

#pragma unroll
        for (int kk = 0; kk < BK; ++kk) {
            float4 av0 = *(const float4*)&As[kk][ty * 8];
            float4 av1 = *(const float4*)&As[kk][ty * 8 + 4];
            float4 bv0 = *(const float4*)&Bs[kk][tx * 8];
            float4 bv1 = *(const float4*)&Bs[kk][tx * 8 + 4];
            float av[8] = {av0.x, av0.y, av0.z, av0.w, av1.x, av1.y, av1.z, av1.w};
            float bv[8] = {bv0.x, bv0.y, bv0.z, bv0.w, bv1.x, bv1.y, bv1.z, bv1.w};
#pragma unroll
            for (int j = 0; j < 8; ++j)
#pragma unroll
                for (int l = 0; l < 8; ++l) acc[j][l] += av[j] * bv[l];
        }
    }

#pragma unroll
    for (int j = 0; j < 8; ++j) {
        float4 v0 = {acc[j][0], acc[j][1], acc[j][2], acc[j][3]};
        float4 v1 = {acc[j][4], acc[j][5], acc[j][6], acc[j][7]};
        float* Cp = C + (size_t)(bm + ty * 8 + j) * 512 + bn + tx * 8;
        *(float4*)(Cp) = v0;
        *(float4*)(Cp + 4) = v1;
    }
}

// ---------------------------------------------------------------------------
// al_src/al_dst: per (v,h) dot of xl[v,h,:] (128) with a_src/a_dst[h,:]
// one wave per node v (4 heads each)
// ---------------------------------------------------------------------------
__global__ __launch_bounds__(256) void gat_al(
    const float* __restrict__ xl, const float* __restrict__ asrc,
    const float* __restrict__ adst, float* __restrict__ als,
    float* __restrict__ ald)
{
    int w = threadIdx.x >> 6, lane = threadIdx.x & 63;
    int v = blockIdx.x * 4 + w;
    const float* xv = xl + (size_t)v * 512;
#pragma unroll
    for (int h = 0; h < 4; ++h) {
        float x0 = xv[h * 128 + lane], x1 = xv[h * 128 + 64 + lane];
        float ps = x0 * asrc[h * 128 + lane] + x1 * asrc[h * 128 + 64 + lane];
        float pd = x0 * adst[h * 128 + lane] + x1 * adst[h * 128 + 64 + lane];
#pragma unroll
        for (int off = 32; off; off >>= 1) {
            ps += __shfl_xor(ps, off);
            pd += __shfl_xor(pd, off);
        }
        if (lane == 0) { als[v * 4 + h] = ps; ald[v * 4 + h] = pd; }
    }
}

// ---------------------------------------------------------------------------
// GAT aggregation: block per dst node. wave w = head h computes masked
// softmax weights; 256 threads gather sum_s w[s]*xl[src].
// LAYER 1: concat + bias + relu -> [V,512]
// LAYER 2: head mean + bias + relu -> [V,128]
// ---------------------------------------------------------------------------
template <int LAYER>
__global__ __launch_bounds__(256) void gat_agg(
    const float* __restrict__ xl, const float* __restrict__ als,
    const float* __restrict__ ald, const unsigned long long* __restrict__ maskT,
    const float* __restrict__ bias, float* __restrict__ out)
{
    int vb = blockIdx.x;             // b*62 + d
    int b = vb / N_;
    int tid = threadIdx.x;
    int lane = tid & 63, w = tid >> 6;   // wave index == head

    __shared__ float wls[4][64];
    __shared__ float red[512];

    unsigned long long m = maskT[vb];

    bool valid = (lane < N_) && ((m >> lane) & 1ull);
    float alpha = -INFINITY;
    if (valid) {
        float a = als[(size_t)(b * N_ + lane) * 4 + w] + ald[(size_t)vb * 4 + w];
        alpha = (a > 0.f) ? a : 0.2f * a;      // leaky_relu
    }
    float mx = alpha;
#pragma unroll
    for (int off = 32; off; off >>= 1) mx = fmaxf(mx, __shfl_xor(mx, off));
    float ex = valid ? expf(alpha - mx) : 0.f;
    float sm = ex;
#pragma unroll
    for (int off = 32; off; off >>= 1) sm += __shfl_xor(sm, off);
    wls[w][lane] = ex / sm;
    __syncthreads();

    int o0 = tid, o1 = tid + 256;
    int h0 = o0 >> 7, h1 = o1 >> 7;
    float acc0 = 0.f, acc1 = 0.f;
    unsigned long long mm = m;
    while (mm) {
        int s = __ffsll(mm) - 1; mm &= mm - 1;
        const float* xs = xl + (size_t)(b * N_ + s) * 512;
        acc0 += wls[h0][s] * xs[o0];
        acc1 += wls[h1][s] * xs[o1];
    }

    if (LAYER == 1) {
        float v0 = acc0 + bias[o0];
        float v1 = acc1 + bias[o1];
        out[(size_t)vb * 512 + o0] = v0 > 0.f ? v0 : 0.f;
        out[(size_t)vb * 512 + o1] = v1 > 0.f ? v1 : 0.f;
    } else {
        red[o0] = acc0; red[o1] = acc1;
        __syncthreads();
        if (tid < 128) {
            float s4 = (red[tid] + red[128 + tid] + red[256 + tid] +
                        red[384 + tid]) * 0.25f + bias[tid];
            out[(size_t)vb * 128 + tid] = s4 > 0.f ? s4 : 0.f;
        }
    }
}

// ---------------------------------------------------------------------------
extern "C" void kernel_launch(void* const* d_in, const int* in_sizes, int n_in,
                              void* d_out, int out_size, void* d_ws, size_t ws_size,
                              hipStream_t stream)
{
    const float* x    = (const float*)d_in[0];
    // d_in[1] = edge_index (unused)
    const float* W1   = (const float*)d_in[2];
    const float* W2   = (const float*)d_in[3];
    const float* bsp  = (const float*)d_in[4];
    const float* Vsp  = (const float*)d_in[5];
    const float* bnw  = (const float*)d_in[6];
    const float* bnb  = (const float*)d_in[7];
    const float* g1w  = (const float*)d_in[8];
    const float* g1as = (const float*)d_in[9];
    const float* g1ad = (const float*)d_in[10];
    const float* g1b  = (const float*)d_in[11];
    const float* g2w  = (const float*)d_in[12];
    const float* g2as = (const float*)d_in[13];
    const float* g2ad = (const float*)d_in[14];
    const float* g2b  = (const float*)d_in[15];
    float* out = (float*)d_out;

    char* ws = (char*)d_ws;
    size_t off = 0;
    auto alloc = [&](size_t bytes) -> void* {
        void* p = ws + off;
        off += (bytes + 255) & ~(size_t)255;
        return p;
    };
    float* S      = (float*)alloc((size_t)V_ * N_ * 4);        // 7.9 MB
    float* scale  = (float*)alloc(N_ * 4);
    float* shift  = (float*)alloc(N_ * 4);
    unsigned long long* maskT = (unsigned long long*)alloc((size_t)V_ * 8);
    float* xl     = (float*)alloc((size_t)V_ * 512 * 4);       // 65 MB
    float* h1     = (float*)alloc((size_t)V_ * 512 * 4);       // 65 MB
    float* als    = (float*)alloc((size_t)V_ * 4 * 4);
    float* ald    = (float*)alloc((size_t)V_ * 4 * 4);

    zero_u64<<<(V_ + 255) / 256, 256, 0, stream>>>(maskT, V_);
    spatial_S<<<V_, 64, 0, stream>>>(x, W1, W2, bsp, Vsp, S);
    bn_stats<<<N_, 256, 0, stream>>>(S, bnw, bnb, scale, shift);
    topk_mask<<<V_, 64, 0, stream>>>(S, scale, shift, maskT);

    dim3 gg(512 / BN, V_ / BM);   // (4, 248)
    gemm_f32<<<gg, 256, 0, stream>>>(x, g1w, xl);
    gat_al<<<V_ / 4, 256, 0, stream>>>(xl, g1as, g1ad, als, ald);
    gat_agg<1><<<V_, 256, 0, stream>>>(xl, als, ald, maskT, g1b, h1);

    gemm_f32<<<gg, 256, 0, stream>>>(h1, g2w, xl);
    gat_al<<<V_ / 4, 256, 0, stream>>>(xl, g2as, g2ad, als, ald);
    gat_agg<2><<<V_, 256, 0, stream>>>(xl, als, ald, maskT, g2b, out);
}

// Round 2
// 525.047 us; speedup vs baseline: 1.5604x; 1.5604x over previous
//
#include <hip/hip_runtime.h>
#include <math.h>

#define B_ 512
#define N_ 62
#define V_ (B_ * N_)      // 31744
#define TOPK_ 8

typedef __attribute__((ext_vector_type(8))) short bf16x8;
typedef __attribute__((ext_vector_type(4))) float f32x4;

// round-to-nearest-even f32 -> bf16 bits
__device__ __forceinline__ unsigned short bf16rn(float f) {
    unsigned int u = __float_as_uint(f);
    unsigned int r = (u + 0x7fffu + ((u >> 16) & 1u)) >> 16;
    return (unsigned short)r;
}
__device__ __forceinline__ float bf16tof(unsigned short h) {
    return __uint_as_float(((unsigned int)h) << 16);
}

__device__ __forceinline__ void gload16(const void* g, void* l) {
    __builtin_amdgcn_global_load_lds(
        (const __attribute__((address_space(1))) unsigned int*)g,
        (__attribute__((address_space(3))) unsigned int*)l, 16, 0, 0);
}

// ---------------------------------------------------------------------------
// Stage 1: S[b,n,m] = tanh( (einsum('bnct,t',x,W1) @ W2) @ V_sp + b_sp )
// ---------------------------------------------------------------------------
__global__ __launch_bounds__(64) void spatial_S(
    const float* __restrict__ x, const float* __restrict__ W1,
    const float* __restrict__ W2, const float* __restrict__ bsp,
    const float* __restrict__ Vsp, float* __restrict__ S)
{
    int blk = blockIdx.x;            // b*62 + n
    int n = blk % N_;
    int lane = threadIdx.x;          // 0..63
    const float* xr = x + (size_t)blk * 512;   // [8][64] row
    float w1 = W1[lane];

    float y[8];
#pragma unroll
    for (int c = 0; c < 8; ++c) {
        float p = xr[c * 64 + lane] * w1;
#pragma unroll
        for (int off = 32; off; off >>= 1) p += __shfl_xor(p, off);
        y[c] = p;
    }

    __shared__ float pr[N_];
    if (lane < N_) {
        float acc = 0.f;
#pragma unroll
        for (int c = 0; c < 8; ++c) acc += y[c] * W2[c * N_ + lane];
        pr[lane] = acc;
    }
    __syncthreads();
    if (lane < N_) {
        float acc = bsp[n * N_ + lane];
        for (int k = 0; k < N_; ++k) acc += pr[k] * Vsp[k * N_ + lane];
        S[(size_t)blk * N_ + lane] = tanhf(acc);
    }
}

// ---------------------------------------------------------------------------
// Stage 2: BatchNorm1d stats, two-stage (992 partial blocks + finalize)
// ---------------------------------------------------------------------------
__global__ __launch_bounds__(256) void bn_part(
    const float* __restrict__ S, double* __restrict__ part)
{
    int n = blockIdx.x >> 4, slice = blockIdx.x & 15;
    double s = 0.0, s2 = 0.0;
    int i0 = slice * 1984;                    // 16*1984 = 31744
    for (int i = i0 + threadIdx.x; i < i0 + 1984; i += 256) {
        int b = i / N_, m = i - b * N_;
        float v = S[((size_t)b * N_ + n) * N_ + m];
        s += v; s2 += (double)v * v;
    }
    __shared__ double sh[256], sh2[256];
    sh[threadIdx.x] = s; sh2[threadIdx.x] = s2;
    __syncthreads();
    for (int off = 128; off; off >>= 1) {
        if (threadIdx.x < off) {
            sh[threadIdx.x] += sh[threadIdx.x + off];
            sh2[threadIdx.x] += sh2[threadIdx.x + off];
        }
        __syncthreads();
    }
    if (threadIdx.x == 0) {
        part[((size_t)n * 16 + slice) * 2 + 0] = sh[0];
        part[((size_t)n * 16 + slice) * 2 + 1] = sh2[0];
    }
}

__global__ __launch_bounds__(64) void bn_final(
    const double* __restrict__ part, const float* __restrict__ bnw,
    const float* __restrict__ bnb, float* __restrict__ scale,
    float* __restrict__ shift)
{
    int n = threadIdx.x;
    if (n >= N_) return;
    double s = 0.0, s2 = 0.0;
    for (int j = 0; j < 16; ++j) {
        s  += part[((size_t)n * 16 + j) * 2 + 0];
        s2 += part[((size_t)n * 16 + j) * 2 + 1];
    }
    const double cnt = (double)(B_ * N_);
    double mean = s / cnt;
    double var = s2 / cnt - mean * mean;
    float inv = (float)(1.0 / sqrt(var + 1e-5));
    scale[n] = bnw[n] * inv;
    shift[n] = bnb[n] - (float)mean * bnw[n] * inv;
}

// ---------------------------------------------------------------------------
// Stage 3: per-row top-8 -> transposed incoming-edge bitmask maskT
// ---------------------------------------------------------------------------
__global__ __launch_bounds__(64) void topk_mask(
    const float* __restrict__ S, const float* __restrict__ scale,
    const float* __restrict__ shift, unsigned long long* __restrict__ maskT)
{
    int blk = blockIdx.x;            // b*62 + n
    int b = blk / N_, n = blk - b * N_;
    int lane = threadIdx.x;
    float v = (lane < N_) ? S[(size_t)blk * N_ + lane] * scale[n] + shift[n]
                          : -INFINITY;
    bool sel = false;
#pragma unroll
    for (int k = 0; k < TOPK_; ++k) {
        float mv = v; int mi = lane;
#pragma unroll
        for (int off = 32; off; off >>= 1) {
            float ov = __shfl_xor(mv, off);
            int   oi = __shfl_xor(mi, off);
            if (ov > mv || (ov == mv && oi < mi)) { mv = ov; mi = oi; }
        }
        if (lane == mi) { sel = true; v = -INFINITY; }
    }
    unsigned long long row = __ballot(sel) | (1ull << n);  // self loop union
    if (lane < N_ && ((row >> lane) & 1ull))
        atomicOr(&maskT[(size_t)b * N_ + lane], 1ull << n);
}

__global__ __launch_bounds__(256) void zero_u64(unsigned long long* p, int n)
{
    int i = blockIdx.x * 256 + threadIdx.x;
    if (i < n) p[i] = 0ull;
}

// ---------------------------------------------------------------------------
// split fp32 [rows][512] -> bf16 [rows][1024] as [hi | lo]
// one thread per float4
// ---------------------------------------------------------------------------
__global__ __launch_bounds__(256) void split_pair(
    const float* __restrict__ in, unsigned short* __restrict__ out, int total4)
{
    int gid = blockIdx.x * 256 + threadIdx.x;
    if (gid >= total4) return;
    int row = gid >> 7;             // 128 float4 per 512-row
    int c = (gid & 127) * 4;
    float4 v = ((const float4*)in)[gid];
    ushort4 h, l;
    float f;
    h.x = bf16rn(v.x); f = v.x - bf16tof(h.x); l.x = bf16rn(f);
    h.y = bf16rn(v.y); f = v.y - bf16tof(h.y); l.y = bf16rn(f);
    h.z = bf16rn(v.z); f = v.z - bf16tof(h.z); l.z = bf16rn(f);
    h.w = bf16rn(v.w); f = v.w - bf16tof(h.w); l.w = bf16rn(f);
    *(ushort4*)(&out[(size_t)row * 1024 + c])       = h;
    *(ushort4*)(&out[(size_t)row * 1024 + 512 + c]) = l;
}

// ---------------------------------------------------------------------------
// bf16 split-K GEMM:  C[v,o] = sum over virtual K=1536 of A'[v,k]*B'[o,k]
//   A' = [Ah | Al]  (packed [M][1024]),  B' = [Bh | Bl]  ([512][1024])
//   segments: s0 = Ah*Bh, s1 = Ah*Bl, s2 = Al*Bh   (bf16x3 emulation)
// 128x128 tile, BK=64, 4 waves (2x2), 16x16x32 MFMA, acc 4x4 frags.
// global_load_lds width-16 linear dest + inverse-XOR-swizzled source;
// ds_read_b128 XOR-swizzled (c_phys = c_log ^ (row&7)) -> bank-balanced.
// ---------------------------------------------------------------------------
#define KP_ 1024
__global__ __launch_bounds__(256) void gemm_bf16(
    const unsigned short* __restrict__ A2, const unsigned short* __restrict__ Bw,
    float* __restrict__ C)
{
    __shared__ __align__(16) unsigned short smem[16384];  // As 8192 + Bs 8192
    char* As = (char*)smem;            // [128 rows][128 bytes]
    char* Bs = (char*)(smem + 8192);

    int tid = threadIdx.x;
    int lane = tid & 63, w = tid >> 6;

    // XCD-bijective block swizzle: 992 = 8 * 124
    int flat = blockIdx.y * 4 + blockIdx.x;
    int swz = (flat & 7) * 124 + (flat >> 3);
    int by = swz >> 2, bx = swz & 3;
    int bm = by * 128, bn = bx * 128;

    int wr = w >> 1, wc = w & 1;

    f32x4 acc[4][4];
#pragma unroll
    for (int mf = 0; mf < 4; ++mf)
#pragma unroll
        for (int nf = 0; nf < 4; ++nf) acc[mf][nf] = (f32x4){0.f, 0.f, 0.f, 0.f};

    // staging constants: instr i covers rows i*32 + w*8 + (lane>>3), col (lane&7)
    int srow = w * 8 + (lane >> 3);
    int kcol = (lane & 7) ^ (lane >> 3);   // logical 16B-col for this lane's slot
    int ldsoff = w * 1024;                 // + i*4096 (+ lane*16 by HW)

    for (int kt = 0; kt < 24; ++kt) {
        int k0 = (kt & 7) * 64;
        int seg = kt >> 3;
        int aBase = (seg == 2 ? 512 : 0) + k0;
        int bBase = (seg == 1 ? 512 : 0) + k0;
#pragma unroll
        for (int i = 0; i < 4; ++i) {
            int row = i * 32 + srow;
            gload16(A2 + (size_t)(bm + row) * KP_ + aBase + kcol * 8,
                    As + i * 4096 + ldsoff);
            gload16(Bw + (size_t)(bn + row) * KP_ + bBase + kcol * 8,
                    Bs + i * 4096 + ldsoff);
        }
        __syncthreads();   // drains vmcnt -> LDS tile ready

#pragma unroll
        for (int kk = 0; kk < 2; ++kk) {
            bf16x8 af[4], bfr[4];
#pragma unroll
            for (int mf = 0; mf < 4; ++mf)
                af[mf] = *(const bf16x8*)(As + (wr*64 + mf*16 + (lane&15))*128
                                             + ((kk*4 + (lane>>4)) ^ (lane&7))*16);
#pragma unroll
            for (int nf = 0; nf < 4; ++nf)
                bfr[nf] = *(const bf16x8*)(Bs + (wc*64 + nf*16 + (lane&15))*128
                                              + ((kk*4 + (lane>>4)) ^ (lane&7))*16);
#pragma unroll
            for (int mf = 0; mf < 4; ++mf)
#pragma unroll
                for (int nf = 0; nf < 4; ++nf)
                    acc[mf][nf] = __builtin_amdgcn_mfma_f32_16x16x32_bf16(
                        af[mf], bfr[nf], acc[mf][nf], 0, 0, 0);
        }
        __syncthreads();   // protect LDS before next stage
    }

    // epilogue: C/D layout col=lane&15, row=(lane>>4)*4+r
    int r0 = bm + wr * 64 + (lane >> 4) * 4;
    int c0 = bn + wc * 64 + (lane & 15);
#pragma unroll
    for (int mf = 0; mf < 4; ++mf)
#pragma unroll
        for (int nf = 0; nf < 4; ++nf)
#pragma unroll
            for (int r = 0; r < 4; ++r)
                C[(size_t)(r0 + mf * 16 + r) * 512 + c0 + nf * 16] = acc[mf][nf][r];
}

// ---------------------------------------------------------------------------
// al_src/al_dst: per (v,h) dot of xl[v,h,:] (128) with a_src/a_dst[h,:]
// ---------------------------------------------------------------------------
__global__ __launch_bounds__(256) void gat_al(
    const float* __restrict__ xl, const float* __restrict__ asrc,
    const float* __restrict__ adst, float* __restrict__ als,
    float* __restrict__ ald)
{
    int w = threadIdx.x >> 6, lane = threadIdx.x & 63;
    int v = blockIdx.x * 4 + w;
    const float* xv = xl + (size_t)v * 512;
#pragma unroll
    for (int h = 0; h < 4; ++h) {
        float x0 = xv[h * 128 + lane], x1 = xv[h * 128 + 64 + lane];
        float ps = x0 * asrc[h * 128 + lane] + x1 * asrc[h * 128 + 64 + lane];
        float pd = x0 * adst[h * 128 + lane] + x1 * adst[h * 128 + 64 + lane];
#pragma unroll
        for (int off = 32; off; off >>= 1) {
            ps += __shfl_xor(ps, off);
            pd += __shfl_xor(pd, off);
        }
        if (lane == 0) { als[v * 4 + h] = ps; ald[v * 4 + h] = pd; }
    }
}

// ---------------------------------------------------------------------------
// GAT aggregation. LAYER 1: concat+bias+relu, written as bf16 [hi|lo] split
// (feeds gemm_bf16 directly). LAYER 2: head mean+bias+relu -> f32 out.
// ---------------------------------------------------------------------------
template <int LAYER>
__global__ __launch_bounds__(256) void gat_agg(
    const float* __restrict__ xl, const float* __restrict__ als,
    const float* __restrict__ ald, const unsigned long long* __restrict__ maskT,
    const float* __restrict__ bias, void* __restrict__ outp)
{
    int vb = blockIdx.x;             // b*62 + d
    int b = vb / N_;
    int tid = threadIdx.x;
    int lane = tid & 63, w = tid >> 6;   // wave index == head

    __shared__ float wls[4][64];
    __shared__ float red[512];

    unsigned long long m = maskT[vb];

    bool valid = (lane < N_) && ((m >> lane) & 1ull);
    float alpha = -INFINITY;
    if (valid) {
        float a = als[(size_t)(b * N_ + lane) * 4 + w] + ald[(size_t)vb * 4 + w];
        alpha = (a > 0.f) ? a : 0.2f * a;      // leaky_relu
    }
    float mx = alpha;
#pragma unroll
    for (int off = 32; off; off >>= 1) mx = fmaxf(mx, __shfl_xor(mx, off));
    float ex = valid ? expf(alpha - mx) : 0.f;
    float sm = ex;
#pragma unroll
    for (int off = 32; off; off >>= 1) sm += __shfl_xor(sm, off);
    wls[w][lane] = ex / sm;
    __syncthreads();

    int o0 = tid, o1 = tid + 256;
    int h0 = o0 >> 7, h1 = o1 >> 7;
    float acc0 = 0.f, acc1 = 0.f;
    unsigned long long mm = m;
    while (mm) {
        int s = __ffsll(mm) - 1; mm &= mm - 1;
        const float* xs = xl + (size_t)(b * N_ + s) * 512;
        acc0 += wls[h0][s] * xs[o0];
        acc1 += wls[h1][s] * xs[o1];
    }

    if (LAYER == 1) {
        unsigned short* ob = (unsigned short*)outp + (size_t)vb * 1024;
        float v0 = acc0 + bias[o0]; v0 = v0 > 0.f ? v0 : 0.f;
        float v1 = acc1 + bias[o1]; v1 = v1 > 0.f ? v1 : 0.f;
        unsigned short h0b = bf16rn(v0), h1b = bf16rn(v1);
        ob[o0] = h0b; ob[512 + o0] = bf16rn(v0 - bf16tof(h0b));
        ob[o1] = h1b; ob[512 + o1] = bf16rn(v1 - bf16tof(h1b));
    } else {
        red[o0] = acc0; red[o1] = acc1;
        __syncthreads();
        if (tid < 128) {
            float s4 = (red[tid] + red[128 + tid] + red[256 + tid] +
                        red[384 + tid]) * 0.25f + bias[tid];
            ((float*)outp)[(size_t)vb * 128 + tid] = s4 > 0.f ? s4 : 0.f;
        }
    }
}

// ---------------------------------------------------------------------------
extern "C" void kernel_launch(void* const* d_in, const int* in_sizes, int n_in,
                              void* d_out, int out_size, void* d_ws, size_t ws_size,
                              hipStream_t stream)
{
    const float* x    = (const float*)d_in[0];
    const float* W1   = (const float*)d_in[2];
    const float* W2   = (const float*)d_in[3];
    const float* bsp  = (const float*)d_in[4];
    const float* Vsp  = (const float*)d_in[5];
    const float* bnw  = (const float*)d_in[6];
    const float* bnb  = (const float*)d_in[7];
    const float* g1w  = (const float*)d_in[8];
    const float* g1as = (const float*)d_in[9];
    const float* g1ad = (const float*)d_in[10];
    const float* g1b  = (const float*)d_in[11];
    const float* g2w  = (const float*)d_in[12];
    const float* g2as = (const float*)d_in[13];
    const float* g2ad = (const float*)d_in[14];
    const float* g2b  = (const float*)d_in[15];
    float* out = (float*)d_out;

    char* ws = (char*)d_ws;
    size_t off = 0;
    auto alloc = [&](size_t bytes) -> void* {
        void* p = ws + off;
        off += (bytes + 255) & ~(size_t)255;
        return p;
    };
    float* S      = (float*)alloc((size_t)V_ * N_ * 4);          // 7.9 MB
    float* scale  = (float*)alloc(N_ * 4);
    float* shift  = (float*)alloc(N_ * 4);
    double* part  = (double*)alloc((size_t)N_ * 16 * 2 * 8);
    unsigned long long* maskT = (unsigned long long*)alloc((size_t)V_ * 8);
    unsigned short* A2  = (unsigned short*)alloc((size_t)V_ * 1024 * 2);  // 65 MB
    unsigned short* Bw1 = (unsigned short*)alloc((size_t)512 * 1024 * 2); // 1 MB
    unsigned short* Bw2 = (unsigned short*)alloc((size_t)512 * 1024 * 2); // 1 MB
    float* xl     = (float*)alloc((size_t)V_ * 512 * 4);         // 65 MB
    float* als    = (float*)alloc((size_t)V_ * 4 * 4);
    float* ald    = (float*)alloc((size_t)V_ * 4 * 4);

    zero_u64<<<(V_ + 255) / 256, 256, 0, stream>>>(maskT, V_);
    spatial_S<<<V_, 64, 0, stream>>>(x, W1, W2, bsp, Vsp, S);
    bn_part<<<N_ * 16, 256, 0, stream>>>(S, part);
    bn_final<<<1, 64, 0, stream>>>(part, bnw, bnb, scale, shift);
    topk_mask<<<V_, 64, 0, stream>>>(S, scale, shift, maskT);

    split_pair<<<(V_ * 128 + 255) / 256, 256, 0, stream>>>(x, A2, V_ * 128);
    split_pair<<<(512 * 128 + 255) / 256, 256, 0, stream>>>(g1w, Bw1, 512 * 128);
    split_pair<<<(512 * 128 + 255) / 256, 256, 0, stream>>>(g2w, Bw2, 512 * 128);

    dim3 gg(4, 248);
    gemm_bf16<<<gg, 256, 0, stream>>>(A2, Bw1, xl);
    gat_al<<<V_ / 4, 256, 0, stream>>>(xl, g1as, g1ad, als, ald);
    gat_agg<1><<<V_, 256, 0, stream>>>(xl, als, ald, maskT, g1b, A2);

    gemm_bf16<<<gg, 256, 0, stream>>>(A2, Bw2, xl);
    gat_al<<<V_ / 4, 256, 0, stream>>>(xl, g2as, g2ad, als, ald);
    gat_agg<2><<<V_, 256, 0, stream>>>(xl, als, ald, maskT, g2b, out);
}

// Round 3
// 481.476 us; speedup vs baseline: 1.7016x; 1.0905x over previous
//
#include <hip/hip_runtime.h>
#include <math.h>

#define B_ 512
#define N_ 62
#define V_ (B_ * N_)      // 31744
#define TOPK_ 8

typedef __attribute__((ext_vector_type(8))) short bf16x8;
typedef __attribute__((ext_vector_type(4))) float f32x4;

// round-to-nearest-even f32 -> bf16 bits
__device__ __forceinline__ unsigned short bf16rn(float f) {
    unsigned int u = __float_as_uint(f);
    unsigned int r = (u + 0x7fffu + ((u >> 16) & 1u)) >> 16;
    return (unsigned short)r;
}
__device__ __forceinline__ float bf16tof(unsigned short h) {
    return __uint_as_float(((unsigned int)h) << 16);
}

__device__ __forceinline__ void gload16(const void* g, void* l) {
    __builtin_amdgcn_global_load_lds(
        (const __attribute__((address_space(1))) unsigned int*)g,
        (__attribute__((address_space(3))) unsigned int*)l, 16, 0, 0);
}

// ---------------------------------------------------------------------------
// Stage 1: S[b,n,m] = tanh( (einsum('bnct,t',x,W1) @ W2) @ V_sp + b_sp )
// ---------------------------------------------------------------------------
__global__ __launch_bounds__(64) void spatial_S(
    const float* __restrict__ x, const float* __restrict__ W1,
    const float* __restrict__ W2, const float* __restrict__ bsp,
    const float* __restrict__ Vsp, float* __restrict__ S)
{
    int blk = blockIdx.x;            // b*62 + n
    int n = blk % N_;
    int lane = threadIdx.x;          // 0..63
    const float* xr = x + (size_t)blk * 512;   // [8][64] row
    float w1 = W1[lane];

    float y[8];
#pragma unroll
    for (int c = 0; c < 8; ++c) {
        float p = xr[c * 64 + lane] * w1;
#pragma unroll
        for (int off = 32; off; off >>= 1) p += __shfl_xor(p, off);
        y[c] = p;
    }

    __shared__ float pr[N_];
    if (lane < N_) {
        float acc = 0.f;
#pragma unroll
        for (int c = 0; c < 8; ++c) acc += y[c] * W2[c * N_ + lane];
        pr[lane] = acc;
    }
    __syncthreads();
    if (lane < N_) {
        float acc = bsp[n * N_ + lane];
        for (int k = 0; k < N_; ++k) acc += pr[k] * Vsp[k * N_ + lane];
        S[(size_t)blk * N_ + lane] = tanhf(acc);
    }
}

// ---------------------------------------------------------------------------
// Stage 2: BatchNorm1d stats, two-stage (992 partial blocks + finalize)
// ---------------------------------------------------------------------------
__global__ __launch_bounds__(256) void bn_part(
    const float* __restrict__ S, double* __restrict__ part)
{
    int n = blockIdx.x >> 4, slice = blockIdx.x & 15;
    double s = 0.0, s2 = 0.0;
    int i0 = slice * 1984;                    // 16*1984 = 31744
    for (int i = i0 + threadIdx.x; i < i0 + 1984; i += 256) {
        int b = i / N_, m = i - b * N_;
        float v = S[((size_t)b * N_ + n) * N_ + m];
        s += v; s2 += (double)v * v;
    }
    __shared__ double sh[256], sh2[256];
    sh[threadIdx.x] = s; sh2[threadIdx.x] = s2;
    __syncthreads();
    for (int off = 128; off; off >>= 1) {
        if (threadIdx.x < off) {
            sh[threadIdx.x] += sh[threadIdx.x + off];
            sh2[threadIdx.x] += sh2[threadIdx.x + off];
        }
        __syncthreads();
    }
    if (threadIdx.x == 0) {
        part[((size_t)n * 16 + slice) * 2 + 0] = sh[0];
        part[((size_t)n * 16 + slice) * 2 + 1] = sh2[0];
    }
}

__global__ __launch_bounds__(64) void bn_final(
    const double* __restrict__ part, const float* __restrict__ bnw,
    const float* __restrict__ bnb, float* __restrict__ scale,
    float* __restrict__ shift)
{
    int n = threadIdx.x;
    if (n >= N_) return;
    double s = 0.0, s2 = 0.0;
    for (int j = 0; j < 16; ++j) {
        s  += part[((size_t)n * 16 + j) * 2 + 0];
        s2 += part[((size_t)n * 16 + j) * 2 + 1];
    }
    const double cnt = (double)(B_ * N_);
    double mean = s / cnt;
    double var = s2 / cnt - mean * mean;
    float inv = (float)(1.0 / sqrt(var + 1e-5));
    scale[n] = bnw[n] * inv;
    shift[n] = bnb[n] - (float)mean * bnw[n] * inv;
}

// ---------------------------------------------------------------------------
// Stage 3: per-row top-8 -> transposed incoming-edge bitmask maskT
// ---------------------------------------------------------------------------
__global__ __launch_bounds__(64) void topk_mask(
    const float* __restrict__ S, const float* __restrict__ scale,
    const float* __restrict__ shift, unsigned long long* __restrict__ maskT)
{
    int blk = blockIdx.x;            // b*62 + n
    int b = blk / N_, n = blk - b * N_;
    int lane = threadIdx.x;
    float v = (lane < N_) ? S[(size_t)blk * N_ + lane] * scale[n] + shift[n]
                          : -INFINITY;
    bool sel = false;
#pragma unroll
    for (int k = 0; k < TOPK_; ++k) {
        float mv = v; int mi = lane;
#pragma unroll
        for (int off = 32; off; off >>= 1) {
            float ov = __shfl_xor(mv, off);
            int   oi = __shfl_xor(mi, off);
            if (ov > mv || (ov == mv && oi < mi)) { mv = ov; mi = oi; }
        }
        if (lane == mi) { sel = true; v = -INFINITY; }
    }
    unsigned long long row = __ballot(sel) | (1ull << n);  // self loop union
    if (lane < N_ && ((row >> lane) & 1ull))
        atomicOr(&maskT[(size_t)b * N_ + lane], 1ull << n);
}

__global__ __launch_bounds__(256) void zero_u64(unsigned long long* p, int n)
{
    int i = blockIdx.x * 256 + threadIdx.x;
    if (i < n) p[i] = 0ull;
}

// ---------------------------------------------------------------------------
// split fp32 -> bf16 hi only (one thread per float4)
// ---------------------------------------------------------------------------
__global__ __launch_bounds__(256) void split_hi(
    const float* __restrict__ in, unsigned short* __restrict__ out, int total4)
{
    int gid = blockIdx.x * 256 + threadIdx.x;
    if (gid >= total4) return;
    float4 v = ((const float4*)in)[gid];
    ushort4 h;
    h.x = bf16rn(v.x); h.y = bf16rn(v.y); h.z = bf16rn(v.z); h.w = bf16rn(v.w);
    ((ushort4*)out)[gid] = h;
}

// split fp32 [rows][512] -> bf16 [rows][1024] as [hi | lo]  (weights)
__global__ __launch_bounds__(256) void split_pair(
    const float* __restrict__ in, unsigned short* __restrict__ out, int total4)
{
    int gid = blockIdx.x * 256 + threadIdx.x;
    if (gid >= total4) return;
    int row = gid >> 7;
    int c = (gid & 127) * 4;
    float4 v = ((const float4*)in)[gid];
    ushort4 h, l;
    float f;
    h.x = bf16rn(v.x); f = v.x - bf16tof(h.x); l.x = bf16rn(f);
    h.y = bf16rn(v.y); f = v.y - bf16tof(h.y); l.y = bf16rn(f);
    h.z = bf16rn(v.z); f = v.z - bf16tof(h.z); l.z = bf16rn(f);
    h.w = bf16rn(v.w); f = v.w - bf16tof(h.w); l.w = bf16rn(f);
    *(ushort4*)(&out[(size_t)row * 1024 + c])       = h;
    *(ushort4*)(&out[(size_t)row * 1024 + 512 + c]) = l;
}

// ---------------------------------------------------------------------------
// 2-term split GEMM:  C = Ah * (Bh + Bl)^T over virtual K = 1024
//   Ah: [M][512] bf16 (hi of A), Bw: [512][1024] = [Bh | Bl]
//   out Cs: [M][1024] split (hi|lo) bf16 of the f32 result.
// 128x128 tile, BK=64, 4 waves, 16x16x32 MFMA. global_load_lds width 16,
// linear LDS dest + inverse-XOR-swizzled source; reads XOR-swizzled.
// ---------------------------------------------------------------------------
__global__ __launch_bounds__(256) void gemm_bf16(
    const unsigned short* __restrict__ Ah, const unsigned short* __restrict__ Bw,
    unsigned short* __restrict__ Cs)
{
    __shared__ __align__(16) unsigned short smem[16384];  // As 8192 + Bs 8192
    char* As = (char*)smem;            // [128 rows][128 bytes]
    char* Bs = (char*)(smem + 8192);

    int tid = threadIdx.x;
    int lane = tid & 63, w = tid >> 6;

    // XCD-bijective block swizzle: 992 = 8 * 124
    int flat = blockIdx.y * 4 + blockIdx.x;
    int swz = (flat & 7) * 124 + (flat >> 3);
    int by = swz >> 2, bx = swz & 3;
    int bm = by * 128, bn = bx * 128;

    int wr = w >> 1, wc = w & 1;

    f32x4 acc[4][4];
#pragma unroll
    for (int mf = 0; mf < 4; ++mf)
#pragma unroll
        for (int nf = 0; nf < 4; ++nf) acc[mf][nf] = (f32x4){0.f, 0.f, 0.f, 0.f};

    int srow = w * 8 + (lane >> 3);
    int kcol = (lane & 7) ^ (lane >> 3);   // inverse-swizzled global 16B col
    int ldsoff = w * 1024;

    for (int kt = 0; kt < 16; ++kt) {
        int k0 = (kt & 7) * 64;
        int bBase = (kt >> 3) * 512 + k0;  // seg0=Bh, seg1=Bl
#pragma unroll
        for (int i = 0; i < 4; ++i) {
            int row = i * 32 + srow;
            gload16(Ah + (size_t)(bm + row) * 512 + k0 + kcol * 8,
                    As + i * 4096 + ldsoff);
            gload16(Bw + (size_t)(bn + row) * 1024 + bBase + kcol * 8,
                    Bs + i * 4096 + ldsoff);
        }
        __syncthreads();

#pragma unroll
        for (int kk = 0; kk < 2; ++kk) {
            bf16x8 af[4], bfr[4];
#pragma unroll
            for (int mf = 0; mf < 4; ++mf)
                af[mf] = *(const bf16x8*)(As + (wr*64 + mf*16 + (lane&15))*128
                                             + ((kk*4 + (lane>>4)) ^ (lane&7))*16);
#pragma unroll
            for (int nf = 0; nf < 4; ++nf)
                bfr[nf] = *(const bf16x8*)(Bs + (wc*64 + nf*16 + (lane&15))*128
                                              + ((kk*4 + (lane>>4)) ^ (lane&7))*16);
#pragma unroll
            for (int mf = 0; mf < 4; ++mf)
#pragma unroll
                for (int nf = 0; nf < 4; ++nf)
                    acc[mf][nf] = __builtin_amdgcn_mfma_f32_16x16x32_bf16(
                        af[mf], bfr[nf], acc[mf][nf], 0, 0, 0);
        }
        __syncthreads();
    }

    // epilogue: write split (hi|lo).  C/D layout col=lane&15, row=(lane>>4)*4+r
    int r0 = bm + wr * 64 + (lane >> 4) * 4;
    int c0 = bn + wc * 64 + (lane & 15);
#pragma unroll
    for (int mf = 0; mf < 4; ++mf)
#pragma unroll
        for (int nf = 0; nf < 4; ++nf)
#pragma unroll
            for (int r = 0; r < 4; ++r) {
                float v = acc[mf][nf][r];
                unsigned short h = bf16rn(v);
                unsigned short l = bf16rn(v - bf16tof(h));
                size_t row = (size_t)(r0 + mf * 16 + r);
                Cs[row * 1024 + c0 + nf * 16] = h;
                Cs[row * 1024 + 512 + c0 + nf * 16] = l;
            }
}

// ---------------------------------------------------------------------------
// Fused GAT layer: per-batch block (512 threads = 8 waves).
//  A: al_src/al_dst for the batch's 62 nodes (fused gat_al)
//  B: masked-softmax weights w[h][s][d] into LDS
//  C: thread-per-column aggregation, acc[62] in registers, xl read once
//  epilogue L1: +bias, relu -> bf16 hi [V][512]
//  epilogue L2: head mean +bias, relu -> f32 [V][128]
// ---------------------------------------------------------------------------
template <int LAYER>
__global__ __launch_bounds__(512, 4) void gat_agg2(
    const unsigned short* __restrict__ XL,   // [V][1024] hi|lo
    const float* __restrict__ asrc, const float* __restrict__ adst,
    const unsigned long long* __restrict__ maskT,
    const float* __restrict__ bias, void* __restrict__ outp)
{
    __shared__ __align__(16) float smem[16368];   // 65472 B
    float* wls = smem;                 // [4][62][64] = 15872 floats
    float* shs = smem + 15872;         // als 248
    float* shd = smem + 15872 + 248;   // ald 248

    int b = blockIdx.x;
    int tid = threadIdx.x;
    int lane = tid & 63, w = tid >> 6;
    const unsigned short* base = XL + (size_t)b * N_ * 1024;

    // ---- phase A: al_src/al_dst (248 tasks = node s x head h) ----
    for (int t = w; t < 248; t += 8) {
        int s = t >> 2, h = t & 3;
        const unsigned short* xv = base + (size_t)s * 1024 + h * 128;
        float x0 = bf16tof(xv[lane])      + bf16tof(xv[512 + lane]);
        float x1 = bf16tof(xv[64 + lane]) + bf16tof(xv[576 + lane]);
        float ps = x0 * asrc[h * 128 + lane] + x1 * asrc[h * 128 + 64 + lane];
        float pd = x0 * adst[h * 128 + lane] + x1 * adst[h * 128 + 64 + lane];
#pragma unroll
        for (int off = 32; off; off >>= 1) {
            ps += __shfl_xor(ps, off);
            pd += __shfl_xor(pd, off);
        }
        if (lane == 0) { shs[t] = ps; shd[t] = pd; }
    }
    __syncthreads();

    // ---- phase B: masked softmax weights (task = dst d x head h) ----
    for (int t = w; t < 248; t += 8) {
        int d = t >> 2, h = t & 3;
        unsigned long long m = maskT[(size_t)b * N_ + d];
        bool valid = (lane < N_) && ((m >> lane) & 1ull);
        float a = -INFINITY;
        if (valid) {
            float raw = shs[lane * 4 + h] + shd[d * 4 + h];
            a = (raw > 0.f) ? raw : 0.2f * raw;
        }
        float mx = a;
#pragma unroll
        for (int off = 32; off; off >>= 1) mx = fmaxf(mx, __shfl_xor(mx, off));
        float ex = valid ? expf(a - mx) : 0.f;
        float sm = ex;
#pragma unroll
        for (int off = 32; off; off >>= 1) sm += __shfl_xor(sm, off);
        if (lane < N_) wls[((size_t)h * N_ + lane) * 64 + d] = ex / sm;
    }
    __syncthreads();

    // ---- phase C: aggregation, thread = column, acc over all 62 dst ----
    int hc = tid >> 7;                 // head of this column
    float acc[62];
#pragma unroll
    for (int d = 0; d < 62; ++d) acc[d] = 0.f;

    for (int s = 0; s < N_; ++s) {
        float x = bf16tof(base[(size_t)s * 1024 + tid])
                + bf16tof(base[(size_t)s * 1024 + 512 + tid]);
        const float* wp = &wls[((size_t)hc * N_ + s) * 64];
#pragma unroll
        for (int g = 0; g < 15; ++g) {
            float4 w4 = *(const float4*)(wp + g * 4);
            acc[4*g+0] += w4.x * x;
            acc[4*g+1] += w4.y * x;
            acc[4*g+2] += w4.z * x;
            acc[4*g+3] += w4.w * x;
        }
        float2 w2 = *(const float2*)(wp + 60);
        acc[60] += w2.x * x;
        acc[61] += w2.y * x;
    }

    if (LAYER == 1) {
        float bct = bias[tid];
        unsigned short* H = (unsigned short*)outp + (size_t)b * N_ * 512;
#pragma unroll
        for (int d = 0; d < 62; ++d) {
            float v = acc[d] + bct;
            v = v > 0.f ? v : 0.f;
            H[(size_t)d * 512 + tid] = bf16rn(v);
        }
    } else {
        __syncthreads();               // wls no longer needed by any wave
        float* red = smem;             // reuse 16x512 f32 = 8192 floats
        float* outf = (float*)outp;
#pragma unroll
        for (int d0 = 0; d0 < 64; d0 += 16) {
#pragma unroll
            for (int di = 0; di < 16; ++di) {
                int d = d0 + di;
                if (d < 62) red[di * 512 + tid] = acc[d];
            }
            __syncthreads();
            int cnt = (62 - d0) < 16 ? (62 - d0) : 16;
            for (int i = tid; i < cnt * 128; i += 512) {
                int di = i >> 7, c = i & 127;
                float s4 = (red[di*512 + c] + red[di*512 + 128 + c] +
                            red[di*512 + 256 + c] + red[di*512 + 384 + c]) * 0.25f
                           + bias[c];
                outf[((size_t)b * N_ + d0 + di) * 128 + c] = s4 > 0.f ? s4 : 0.f;
            }
            __syncthreads();
        }
    }
}

// ---------------------------------------------------------------------------
extern "C" void kernel_launch(void* const* d_in, const int* in_sizes, int n_in,
                              void* d_out, int out_size, void* d_ws, size_t ws_size,
                              hipStream_t stream)
{
    const float* x    = (const float*)d_in[0];
    const float* W1   = (const float*)d_in[2];
    const float* W2   = (const float*)d_in[3];
    const float* bsp  = (const float*)d_in[4];
    const float* Vsp  = (const float*)d_in[5];
    const float* bnw  = (const float*)d_in[6];
    const float* bnb  = (const float*)d_in[7];
    const float* g1w  = (const float*)d_in[8];
    const float* g1as = (const float*)d_in[9];
    const float* g1ad = (const float*)d_in[10];
    const float* g1b  = (const float*)d_in[11];
    const float* g2w  = (const float*)d_in[12];
    const float* g2as = (const float*)d_in[13];
    const float* g2ad = (const float*)d_in[14];
    const float* g2b  = (const float*)d_in[15];
    float* out = (float*)d_out;

    char* ws = (char*)d_ws;
    size_t off = 0;
    auto alloc = [&](size_t bytes) -> void* {
        void* p = ws + off;
        off += (bytes + 255) & ~(size_t)255;
        return p;
    };
    float* S      = (float*)alloc((size_t)V_ * N_ * 4);          // 7.9 MB
    float* scale  = (float*)alloc(N_ * 4);
    float* shift  = (float*)alloc(N_ * 4);
    double* part  = (double*)alloc((size_t)N_ * 16 * 2 * 8);
    unsigned long long* maskT = (unsigned long long*)alloc((size_t)V_ * 8);
    unsigned short* A2  = (unsigned short*)alloc((size_t)V_ * 512 * 2);   // 32.5 MB
    unsigned short* Bw1 = (unsigned short*)alloc((size_t)512 * 1024 * 2); // 1 MB
    unsigned short* Bw2 = (unsigned short*)alloc((size_t)512 * 1024 * 2); // 1 MB
    unsigned short* XL  = (unsigned short*)alloc((size_t)V_ * 1024 * 2);  // 65 MB
    unsigned short* H1  = (unsigned short*)alloc((size_t)V_ * 512 * 2);   // 32.5 MB

    zero_u64<<<(V_ + 255) / 256, 256, 0, stream>>>(maskT, V_);
    spatial_S<<<V_, 64, 0, stream>>>(x, W1, W2, bsp, Vsp, S);
    bn_part<<<N_ * 16, 256, 0, stream>>>(S, part);
    bn_final<<<1, 64, 0, stream>>>(part, bnw, bnb, scale, shift);
    topk_mask<<<V_, 64, 0, stream>>>(S, scale, shift, maskT);

    split_hi<<<(V_ * 128 + 255) / 256, 256, 0, stream>>>(x, A2, V_ * 128);
    split_pair<<<(512 * 128 + 255) / 256, 256, 0, stream>>>(g1w, Bw1, 512 * 128);
    split_pair<<<(512 * 128 + 255) / 256, 256, 0, stream>>>(g2w, Bw2, 512 * 128);

    dim3 gg(4, 248);
    gemm_bf16<<<gg, 256, 0, stream>>>(A2, Bw1, XL);
    gat_agg2<1><<<B_, 512, 0, stream>>>(XL, g1as, g1ad, maskT, g1b, H1);

    gemm_bf16<<<gg, 256, 0, stream>>>(H1, Bw2, XL);
    gat_agg2<2><<<B_, 512, 0, stream>>>(XL, g2as, g2ad, maskT, g2b, out);
}

// Round 6
// 407.561 us; speedup vs baseline: 2.0102x; 1.1814x over previous
//
#include <hip/hip_runtime.h>
#include <math.h>

#define B_ 512
#define N_ 62
#define V_ (B_ * N_)      // 31744
#define TOPK_ 8

typedef __attribute__((ext_vector_type(8))) short bf16x8;
typedef __attribute__((ext_vector_type(4))) float f32x4;

// round-to-nearest-even f32 -> bf16 bits
__device__ __forceinline__ unsigned short bf16rn(float f) {
    unsigned int u = __float_as_uint(f);
    unsigned int r = (u + 0x7fffu + ((u >> 16) & 1u)) >> 16;
    return (unsigned short)r;
}
__device__ __forceinline__ float bf16tof(unsigned short h) {
    return __uint_as_float(((unsigned int)h) << 16);
}

__device__ __forceinline__ void gload16(const void* g, void* l) {
    __builtin_amdgcn_global_load_lds(
        (const __attribute__((address_space(1))) unsigned int*)g,
        (__attribute__((address_space(3))) unsigned int*)l, 16, 0, 0);
}

// ---------------------------------------------------------------------------
// Stage 1: S[b,n,m] = tanh( (einsum('bnct,t',x,W1) @ W2) @ V_sp + b_sp )
// Also emits A2 = bf16(x) (fused split_hi: x is only read once).
// ---------------------------------------------------------------------------
__global__ __launch_bounds__(64) void spatial_S(
    const float* __restrict__ x, const float* __restrict__ W1,
    const float* __restrict__ W2, const float* __restrict__ bsp,
    const float* __restrict__ Vsp, float* __restrict__ S,
    unsigned short* __restrict__ A2)
{
    int blk = blockIdx.x;            // b*62 + n
    int n = blk % N_;
    int lane = threadIdx.x;          // 0..63
    const float* xr = x + (size_t)blk * 512;   // [8][64] row
    float w1 = W1[lane];

    float y[8];
#pragma unroll
    for (int c = 0; c < 8; ++c) {
        float xv = xr[c * 64 + lane];
        A2[(size_t)blk * 512 + c * 64 + lane] = bf16rn(xv);
        float p = xv * w1;
#pragma unroll
        for (int off = 32; off; off >>= 1) p += __shfl_xor(p, off);
        y[c] = p;
    }

    __shared__ float pr[N_];
    if (lane < N_) {
        float acc = 0.f;
#pragma unroll
        for (int c = 0; c < 8; ++c) acc += y[c] * W2[c * N_ + lane];
        pr[lane] = acc;
    }
    __syncthreads();
    if (lane < N_) {
        float acc = bsp[n * N_ + lane];
        for (int k = 0; k < N_; ++k) acc += pr[k] * Vsp[k * N_ + lane];
        S[(size_t)blk * N_ + lane] = tanhf(acc);
    }
}

// ---------------------------------------------------------------------------
// Stage 2: BatchNorm1d stats, two-stage
// ---------------------------------------------------------------------------
__global__ __launch_bounds__(256) void bn_part(
    const float* __restrict__ S, double* __restrict__ part)
{
    int n = blockIdx.x >> 4, slice = blockIdx.x & 15;
    double s = 0.0, s2 = 0.0;
    int i0 = slice * 1984;                    // 16*1984 = 31744
    for (int i = i0 + threadIdx.x; i < i0 + 1984; i += 256) {
        int b = i / N_, m = i - b * N_;
        float v = S[((size_t)b * N_ + n) * N_ + m];
        s += v; s2 += (double)v * v;
    }
    __shared__ double sh[256], sh2[256];
    sh[threadIdx.x] = s; sh2[threadIdx.x] = s2;
    __syncthreads();
    for (int off = 128; off; off >>= 1) {
        if (threadIdx.x < off) {
            sh[threadIdx.x] += sh[threadIdx.x + off];
            sh2[threadIdx.x] += sh2[threadIdx.x + off];
        }
        __syncthreads();
    }
    if (threadIdx.x == 0) {
        part[((size_t)n * 16 + slice) * 2 + 0] = sh[0];
        part[((size_t)n * 16 + slice) * 2 + 1] = sh2[0];
    }
}

__global__ __launch_bounds__(64) void bn_final(
    const double* __restrict__ part, const float* __restrict__ bnw,
    const float* __restrict__ bnb, float* __restrict__ scale,
    float* __restrict__ shift)
{
    int n = threadIdx.x;
    if (n >= N_) return;
    double s = 0.0, s2 = 0.0;
    for (int j = 0; j < 16; ++j) {
        s  += part[((size_t)n * 16 + j) * 2 + 0];
        s2 += part[((size_t)n * 16 + j) * 2 + 1];
    }
    const double cnt = (double)(B_ * N_);
    double mean = s / cnt;
    double var = s2 / cnt - mean * mean;
    float inv = (float)(1.0 / sqrt(var + 1e-5));
    scale[n] = bnw[n] * inv;
    shift[n] = bnb[n] - (float)mean * bnw[n] * inv;
}

// ---------------------------------------------------------------------------
// Stage 3: per-row top-8 -> transposed incoming-edge bitmask maskT
// ---------------------------------------------------------------------------
__global__ __launch_bounds__(64) void topk_mask(
    const float* __restrict__ S, const float* __restrict__ scale,
    const float* __restrict__ shift, unsigned long long* __restrict__ maskT)
{
    int blk = blockIdx.x;            // b*62 + n
    int b = blk / N_, n = blk - b * N_;
    int lane = threadIdx.x;
    float v = (lane < N_) ? S[(size_t)blk * N_ + lane] * scale[n] + shift[n]
                          : -INFINITY;
    bool sel = false;
#pragma unroll
    for (int k = 0; k < TOPK_; ++k) {
        float mv = v; int mi = lane;
#pragma unroll
        for (int off = 32; off; off >>= 1) {
            float ov = __shfl_xor(mv, off);
            int   oi = __shfl_xor(mi, off);
            if (ov > mv || (ov == mv && oi < mi)) { mv = ov; mi = oi; }
        }
        if (lane == mi) { sel = true; v = -INFINITY; }
    }
    unsigned long long row = __ballot(sel) | (1ull << n);  // self loop union
    if (lane < N_ && ((row >> lane) & 1ull))
        atomicOr(&maskT[(size_t)b * N_ + lane], 1ull << n);
}

__global__ __launch_bounds__(256) void zero_u64(unsigned long long* p, int n)
{
    int i = blockIdx.x * 256 + threadIdx.x;
    if (i < n) p[i] = 0ull;
}

// split fp32 [rows][512] -> bf16 [rows][1024] as [hi | lo]  (weights only)
__global__ __launch_bounds__(256) void split_pair(
    const float* __restrict__ in, unsigned short* __restrict__ out, int total4)
{
    int gid = blockIdx.x * 256 + threadIdx.x;
    if (gid >= total4) return;
    int row = gid >> 7;
    int c = (gid & 127) * 4;
    float4 v = ((const float4*)in)[gid];
    ushort4 h, l;
    float f;
    h.x = bf16rn(v.x); f = v.x - bf16tof(h.x); l.x = bf16rn(f);
    h.y = bf16rn(v.y); f = v.y - bf16tof(h.y); l.y = bf16rn(f);
    h.z = bf16rn(v.z); f = v.z - bf16tof(h.z); l.z = bf16rn(f);
    h.w = bf16rn(v.w); f = v.w - bf16tof(h.w); l.w = bf16rn(f);
    *(ushort4*)(&out[(size_t)row * 1024 + c])       = h;
    *(ushort4*)(&out[(size_t)row * 1024 + 512 + c]) = l;
}

// ---------------------------------------------------------------------------
// 2-term split GEMM:  C = Ah * (Bh + Bl)^T over virtual K = 1024
//   out Cs: [M][1024] split (hi|lo) bf16 of the f32 result.
// (verified passing in rounds 2-3)
// ---------------------------------------------------------------------------
__global__ __launch_bounds__(256) void gemm_bf16(
    const unsigned short* __restrict__ Ah, const unsigned short* __restrict__ Bw,
    unsigned short* __restrict__ Cs)
{
    __shared__ __align__(16) unsigned short smem[16384];  // As 8192 + Bs 8192
    char* As = (char*)smem;            // [128 rows][128 bytes]
    char* Bs = (char*)(smem + 8192);

    int tid = threadIdx.x;
    int lane = tid & 63, w = tid >> 6;

    // XCD-bijective block swizzle: 992 = 8 * 124
    int flat = blockIdx.y * 4 + blockIdx.x;
    int swz = (flat & 7) * 124 + (flat >> 3);
    int by = swz >> 2, bx = swz & 3;
    int bm = by * 128, bn = bx * 128;

    int wr = w >> 1, wc = w & 1;

    f32x4 acc[4][4];
#pragma unroll
    for (int mf = 0; mf < 4; ++mf)
#pragma unroll
        for (int nf = 0; nf < 4; ++nf) acc[mf][nf] = (f32x4){0.f, 0.f, 0.f, 0.f};

    int srow = w * 8 + (lane >> 3);
    int kcol = (lane & 7) ^ (lane >> 3);   // inverse-swizzled global 16B col
    int ldsoff = w * 1024;

    for (int kt = 0; kt < 16; ++kt) {
        int k0 = (kt & 7) * 64;
        int bBase = (kt >> 3) * 512 + k0;  // seg0=Bh, seg1=Bl
#pragma unroll
        for (int i = 0; i < 4; ++i) {
            int row = i * 32 + srow;
            gload16(Ah + (size_t)(bm + row) * 512 + k0 + kcol * 8,
                    As + i * 4096 + ldsoff);
            gload16(Bw + (size_t)(bn + row) * 1024 + bBase + kcol * 8,
                    Bs + i * 4096 + ldsoff);
        }
        __syncthreads();

#pragma unroll
        for (int kk = 0; kk < 2; ++kk) {
            bf16x8 af[4], bfr[4];
#pragma unroll
            for (int mf = 0; mf < 4; ++mf)
                af[mf] = *(const bf16x8*)(As + (wr*64 + mf*16 + (lane&15))*128
                                             + ((kk*4 + (lane>>4)) ^ (lane&7))*16);
#pragma unroll
            for (int nf = 0; nf < 4; ++nf)
                bfr[nf] = *(const bf16x8*)(Bs + (wc*64 + nf*16 + (lane&15))*128
                                              + ((kk*4 + (lane>>4)) ^ (lane&7))*16);
#pragma unroll
            for (int mf = 0; mf < 4; ++mf)
#pragma unroll
                for (int nf = 0; nf < 4; ++nf)
                    acc[mf][nf] = __builtin_amdgcn_mfma_f32_16x16x32_bf16(
                        af[mf], bfr[nf], acc[mf][nf], 0, 0, 0);
        }
        __syncthreads();
    }

    int r0 = bm + wr * 64 + (lane >> 4) * 4;
    int c0 = bn + wc * 64 + (lane & 15);
#pragma unroll
    for (int mf = 0; mf < 4; ++mf)
#pragma unroll
        for (int nf = 0; nf < 4; ++nf)
#pragma unroll
            for (int r = 0; r < 4; ++r) {
                float v = acc[mf][nf][r];
                unsigned short h = bf16rn(v);
                unsigned short l = bf16rn(v - bf16tof(h));
                size_t row = (size_t)(r0 + mf * 16 + r);
                Cs[row * 1024 + c0 + nf * 16] = h;
                Cs[row * 1024 + 512 + c0 + nf * 16] = l;
            }
}

// ---------------------------------------------------------------------------
// MFMA GAT layer: block = batch (512 thr / 8 waves).
//  A: als/ald (global, hi+lo)   B: softmax -> W_att bf16 in LDS (swizzled)
//  C: per head: C[62x128] = W*Xh + W*Xl via 16x16x32 MFMA.
//     A-frag (W) from LDS (gemm-verified pattern); B-frag (X) loaded
//     DIRECTLY from global: each element consumed by exactly one thread,
//     so no LDS staging / transpose needed. No inline asm anywhere.
//  W columns s=62,63 are written 0, so slack-row X reads are harmless.
//  APPLY=1: +bias, relu (layer1).  APPLY=0: raw (layer2, mean later).
// ---------------------------------------------------------------------------
template <int APPLY>
__global__ __launch_bounds__(512, 4) void gat_aggM(
    const unsigned short* __restrict__ XL,   // [V+2][1024] hi|lo
    const float* __restrict__ asrc, const float* __restrict__ adst,
    const unsigned long long* __restrict__ maskT,
    const float* __restrict__ bias,
    unsigned short* __restrict__ H)
{
    // LDS: W_att [4][64 d][64 s] bf16 @0 (32KB, 16B groups XOR-swizzled by d&7)
    //      shs @32768 (248 f32), shd @33760
    __shared__ __align__(16) char lds[34816];
    float* shs = (float*)(lds + 32768);
    float* shd = (float*)(lds + 33760);

    int b = blockIdx.x;
    int tid = threadIdx.x;
    int lane = tid & 63, w = tid >> 6;
    const unsigned short* base = XL + (size_t)b * N_ * 1024;

    // ---- phase A: al_src/al_dst (hi+lo, global) ----
    for (int t = w; t < 248; t += 8) {
        int s = t >> 2, h = t & 3;
        const unsigned short* xv = base + (size_t)s * 1024 + h * 128;
        float x0 = bf16tof(xv[lane])      + bf16tof(xv[512 + lane]);
        float x1 = bf16tof(xv[64 + lane]) + bf16tof(xv[576 + lane]);
        float ps = x0 * asrc[h * 128 + lane] + x1 * asrc[h * 128 + 64 + lane];
        float pd = x0 * adst[h * 128 + lane] + x1 * adst[h * 128 + 64 + lane];
#pragma unroll
        for (int off = 32; off; off >>= 1) {
            ps += __shfl_xor(ps, off);
            pd += __shfl_xor(pd, off);
        }
        if (lane == 0) { shs[t] = ps; shd[t] = pd; }
    }
    __syncthreads();

    // ---- phase B: masked softmax -> W_att (bf16, swizzled; s=62,63 -> 0) ----
    for (int t = w; t < 248; t += 8) {
        int d = t >> 2, h = t & 3;
        unsigned long long m = maskT[(size_t)b * N_ + d];
        bool valid = (lane < N_) && ((m >> lane) & 1ull);
        float a = -INFINITY;
        if (valid) {
            float raw = shs[lane * 4 + h] + shd[d * 4 + h];
            a = (raw > 0.f) ? raw : 0.2f * raw;
        }
        float mx = a;
#pragma unroll
        for (int off = 32; off; off >>= 1) mx = fmaxf(mx, __shfl_xor(mx, off));
        float ex = valid ? expf(a - mx) : 0.f;
        float sm = ex;
#pragma unroll
        for (int off = 32; off; off >>= 1) sm += __shfl_xor(sm, off);
        float wv = valid ? ex / sm : 0.f;
        int addr = h * 8192 + d * 128
                 + (((lane >> 3) ^ (d & 7)) << 4) + ((lane & 7) << 1);
        *(unsigned short*)(lds + addr) = bf16rn(wv);
    }
    __syncthreads();   // W ready; no LDS writes after this point

    int cc = lane & 15, lh = lane >> 4;

    union U8 { unsigned short s[8]; bf16x8 v; };

#pragma unroll
    for (int ch = 0; ch < 4; ++ch) {     // chunk == head
        f32x4 acc[4];
#pragma unroll
        for (int mf = 0; mf < 4; ++mf) acc[mf] = (f32x4){0.f, 0.f, 0.f, 0.f};

        // this thread's column c and its s-rows lh*8..+7 (+32 for kk=1)
        const unsigned short* xp = base + (size_t)(lh * 8) * 1024
                                        + ch * 128 + w * 16 + cc;
#pragma unroll
        for (int kk = 0; kk < 2; ++kk) {
            U8 bh, bl;
#pragma unroll
            for (int j = 0; j < 8; ++j) {
                size_t o = (size_t)(kk * 32 + j) * 1024;
                bh.s[j] = xp[o];            // hi
                bl.s[j] = xp[o + 512];      // lo
            }
            bf16x8 af[4];
#pragma unroll
            for (int mf = 0; mf < 4; ++mf)
                af[mf] = *(const bf16x8*)(lds + ch * 8192
                              + (mf * 16 + cc) * 128
                              + (((kk * 4 + lh) ^ (cc & 7)) << 4));
#pragma unroll
            for (int mf = 0; mf < 4; ++mf) {
                acc[mf] = __builtin_amdgcn_mfma_f32_16x16x32_bf16(
                    af[mf], bh.v, acc[mf], 0, 0, 0);
                acc[mf] = __builtin_amdgcn_mfma_f32_16x16x32_bf16(
                    af[mf], bl.v, acc[mf], 0, 0, 0);
            }
        }

        int c = ch * 128 + w * 16 + cc;
        float bc = APPLY ? bias[c] : 0.f;
#pragma unroll
        for (int mf = 0; mf < 4; ++mf)
#pragma unroll
            for (int r = 0; r < 4; ++r) {
                int d = mf * 16 + lh * 4 + r;
                if (d < N_) {
                    float v = acc[mf][r] + bc;
                    if (APPLY) v = v > 0.f ? v : 0.f;
                    H[(size_t)(b * N_ + d) * 512 + c] = bf16rn(v);
                }
            }
    }
}

// ---------------------------------------------------------------------------
// layer-2 final: out[v][c] = relu(mean_h(H2[v][h*128+c]) + bias[c])  (f32)
// ---------------------------------------------------------------------------
__global__ __launch_bounds__(512) void mean_relu(
    const unsigned short* __restrict__ H2, const float* __restrict__ bias,
    float* __restrict__ out)
{
    int tid = threadIdx.x;
    int v = blockIdx.x * 4 + (tid >> 7);
    int c = tid & 127;
    const unsigned short* t = H2 + (size_t)v * 512;
    float s = bf16tof(t[c]) + bf16tof(t[128 + c]) +
              bf16tof(t[256 + c]) + bf16tof(t[384 + c]);
    s = s * 0.25f + bias[c];
    out[(size_t)v * 128 + c] = s > 0.f ? s : 0.f;
}

// ---------------------------------------------------------------------------
extern "C" void kernel_launch(void* const* d_in, const int* in_sizes, int n_in,
                              void* d_out, int out_size, void* d_ws, size_t ws_size,
                              hipStream_t stream)
{
    const float* x    = (const float*)d_in[0];
    const float* W1   = (const float*)d_in[2];
    const float* W2   = (const float*)d_in[3];
    const float* bsp  = (const float*)d_in[4];
    const float* Vsp  = (const float*)d_in[5];
    const float* bnw  = (const float*)d_in[6];
    const float* bnb  = (const float*)d_in[7];
    const float* g1w  = (const float*)d_in[8];
    const float* g1as = (const float*)d_in[9];
    const float* g1ad = (const float*)d_in[10];
    const float* g1b  = (const float*)d_in[11];
    const float* g2w  = (const float*)d_in[12];
    const float* g2as = (const float*)d_in[13];
    const float* g2ad = (const float*)d_in[14];
    const float* g2b  = (const float*)d_in[15];
    float* out = (float*)d_out;

    char* ws = (char*)d_ws;
    size_t off = 0;
    auto alloc = [&](size_t bytes) -> void* {
        void* p = ws + off;
        off += (bytes + 255) & ~(size_t)255;
        return p;
    };
    float* S      = (float*)alloc((size_t)V_ * N_ * 4);          // 7.9 MB
    float* scale  = (float*)alloc(N_ * 4);
    float* shift  = (float*)alloc(N_ * 4);
    double* part  = (double*)alloc((size_t)N_ * 16 * 2 * 8);
    unsigned long long* maskT = (unsigned long long*)alloc((size_t)V_ * 8);
    unsigned short* A2  = (unsigned short*)alloc((size_t)V_ * 512 * 2);      // 32.5 MB
    unsigned short* Bw1 = (unsigned short*)alloc((size_t)512 * 1024 * 2);    // 1 MB
    unsigned short* Bw2 = (unsigned short*)alloc((size_t)512 * 1024 * 2);    // 1 MB
    unsigned short* XL  = (unsigned short*)alloc((size_t)(V_ + 2) * 1024 * 2); // 65 MB (+slack)
    unsigned short* H1  = (unsigned short*)alloc((size_t)V_ * 512 * 2);      // 32.5 MB
    unsigned short* H2  = (unsigned short*)alloc((size_t)V_ * 512 * 2);      // 32.5 MB

    zero_u64<<<(V_ + 255) / 256, 256, 0, stream>>>(maskT, V_);
    spatial_S<<<V_, 64, 0, stream>>>(x, W1, W2, bsp, Vsp, S, A2);
    bn_part<<<N_ * 16, 256, 0, stream>>>(S, part);
    bn_final<<<1, 64, 0, stream>>>(part, bnw, bnb, scale, shift);
    topk_mask<<<V_, 64, 0, stream>>>(S, scale, shift, maskT);

    split_pair<<<(512 * 128 + 255) / 256, 256, 0, stream>>>(g1w, Bw1, 512 * 128);
    split_pair<<<(512 * 128 + 255) / 256, 256, 0, stream>>>(g2w, Bw2, 512 * 128);

    dim3 gg(4, 248);
    gemm_bf16<<<gg, 256, 0, stream>>>(A2, Bw1, XL);
    gat_aggM<1><<<B_, 512, 0, stream>>>(XL, g1as, g1ad, maskT, g1b, H1);

    gemm_bf16<<<gg, 256, 0, stream>>>(H1, Bw2, XL);
    gat_aggM<0><<<B_, 512, 0, stream>>>(XL, g2as, g2ad, maskT, g2b, H2);
    mean_relu<<<V_ / 4, 512, 0, stream>>>(H2, g2b, out);
}